// Round 2
// baseline (33571.783 us; speedup 1.0000x reference)
//
#include <hip/hip_runtime.h>

#define H 1024
#define I_DIM 128
#define O_DIM 128
#define T_DIM 512
#define B_DIM 64
#define ALPHA 0.2f

typedef short short8 __attribute__((ext_vector_type(8)));
typedef float f32x4 __attribute__((ext_vector_type(4)));

__device__ __forceinline__ unsigned short f2b(float f) {
    union { float f; unsigned u; } x;
    x.f = f;
    unsigned u = x.u;
    return (unsigned short)((u + 0x7FFFu + ((u >> 16) & 1u)) >> 16);
}

__device__ __forceinline__ float tanh_fast(float x) {
    // tanh(x) = 1 - 2/(exp(2x)+1); __expf -> v_exp_f32, rcp -> v_rcp_f32
    float e = __expf(2.0f * x);
    return 1.0f - 2.0f * __builtin_amdgcn_rcpf(e + 1.0f);
}

// Load 8 contiguous f32 and round-to-nearest-even to a bf16 A-fragment.
__device__ __forceinline__ short8 ld8f(const float* __restrict__ p) {
    const float4 a = *(const float4*)p;
    const float4 b = *(const float4*)(p + 4);
    short8 r;
    r[0] = (short)f2b(a.x); r[1] = (short)f2b(a.y);
    r[2] = (short)f2b(a.z); r[3] = (short)f2b(a.w);
    r[4] = (short)f2b(b.x); r[5] = (short)f2b(b.y);
    r[6] = (short)f2b(b.z); r[7] = (short)f2b(b.w);
    return r;
}

// Convert weights f32 -> bf16 once:
//   wrecB[j][k] = bf16(wrec[j][k])              (H x H, same layout)
//   wiT[j][i]   = bf16(wi[i][j])                (H x I, transposed)
//   woutT[o][k] = bf16(wout[k][o])              (O x H, transposed)
__global__ void prep_kernel(const float* __restrict__ wi,
                            const float* __restrict__ wrec,
                            const float* __restrict__ wout,
                            unsigned short* __restrict__ wrecB,
                            unsigned short* __restrict__ wiT,
                            unsigned short* __restrict__ woutT) {
    int idx = blockIdx.x * blockDim.x + threadIdx.x;
    if (idx < H * H) {
        wrecB[idx] = f2b(wrec[idx]);
    } else if (idx < H * H + H * I_DIM) {
        int k = idx - H * H;
        int j = k / I_DIM, i = k % I_DIM;
        wiT[k] = f2b(wi[i * H + j]);
    } else {
        int k = idx - H * H - H * I_DIM;
        int o = k / H, kk = k % H;
        woutT[k] = f2b(wout[kk * O_DIM + o]);
    }
}

// 4 workgroups x 16 batch elements. 8 waves/WG, wave w owns j in [128w, 128w+128).
// h state lives in f32 registers (MFMA C-layout). a = g*tanh(h+b) is exchanged
// through double-buffered LDS (C-layout write -> A-layout ds_read_b128).
__global__ __launch_bounds__(512, 2) void rnn_kernel(
    const float* __restrict__ x,
    const unsigned short* __restrict__ wrecB,
    const float* __restrict__ bb,
    const float* __restrict__ gg,
    const float* __restrict__ h0,
    const unsigned short* __restrict__ wiT,
    const unsigned short* __restrict__ woutT,
    float* __restrict__ out) {
    // +8 pad keeps row stride a multiple of 16B while breaking the worst
    // power-of-two bank aliasing.
    __shared__ unsigned short a_lds[2][16][H + 8];

    const int tid = threadIdx.x;
    const int lane = tid & 63;
    const int wave = tid >> 6;       // 0..7
    const int n = lane & 15;         // MFMA m/n index
    const int q = lane >> 4;         // 0..3 (quad)
    const int j0 = wave * 128;
    const int b0 = blockIdx.x * 16;

    float gvr[8], bvr[8], hreg[8][4];

    // init: load per-lane g, b, h0; write a0 = g*tanh(h0+b) (batch-broadcast)
#pragma unroll
    for (int jt = 0; jt < 8; ++jt) {
        int j = j0 + jt * 16 + n;
        gvr[jt] = gg[j];
        bvr[jt] = bb[j];
        float h0v = h0[j];
#pragma unroll
        for (int r = 0; r < 4; ++r) hreg[jt][r] = h0v;
        unsigned short a0 = f2b(gvr[jt] * tanh_fast(h0v + bvr[jt]));
#pragma unroll
        for (int r = 0; r < 4; ++r) a_lds[0][q * 4 + r][j] = a0;
    }
    __syncthreads();

    // out[:, t, :] = a_t @ wout ; wave w computes o in [16w, 16w+16)
    auto do_out = [&](int t, int cur) {
        f32x4 oacc = {0.f, 0.f, 0.f, 0.f};
#pragma unroll 4
        for (int kt = 0; kt < 32; ++kt) {
            short8 af = *(const short8*)&a_lds[cur][n][kt * 32 + q * 8];
            short8 bf = *(const short8*)&woutT[(size_t)(wave * 16 + n) * H + kt * 32 + q * 8];
            oacc = __builtin_amdgcn_mfma_f32_16x16x32_bf16(af, bf, oacc, 0, 0, 0);
        }
#pragma unroll
        for (int r = 0; r < 4; ++r) {
            out[(size_t)(b0 + q * 4 + r) * (T_DIM * O_DIM) + (size_t)t * O_DIM + wave * 16 + n] =
                oacc[r];
        }
    };

    do_out(0, 0);

    for (int t = 1; t < T_DIM; ++t) {
        const int pr = (t - 1) & 1, cur = t & 1;
        f32x4 acc[8];
#pragma unroll
        for (int jt = 0; jt < 8; ++jt) acc[jt] = (f32x4){0.f, 0.f, 0.f, 0.f};

        // z = a_{t-1} @ wrec^T : B[k][n] = wrec[j][k] -> contiguous row reads
#pragma unroll 2
        for (int kt = 0; kt < 32; ++kt) {
            short8 af = *(const short8*)&a_lds[pr][n][kt * 32 + q * 8];
#pragma unroll
            for (int jt = 0; jt < 8; ++jt) {
                short8 bf = *(const short8*)&wrecB[(size_t)(j0 + jt * 16 + n) * H + kt * 32 + q * 8];
                acc[jt] = __builtin_amdgcn_mfma_f32_16x16x32_bf16(af, bf, acc[jt], 0, 0, 0);
            }
        }

        // + x_{t-1} @ wi  (x is f32; convert fragments inline)
        const float* xrow = x + ((size_t)(b0 + n) * T_DIM + (t - 1)) * I_DIM;
#pragma unroll
        for (int kt = 0; kt < 4; ++kt) {
            short8 af = ld8f(&xrow[kt * 32 + q * 8]);
#pragma unroll
            for (int jt = 0; jt < 8; ++jt) {
                short8 bf = *(const short8*)&wiT[(size_t)(j0 + jt * 16 + n) * I_DIM + kt * 32 + q * 8];
                acc[jt] = __builtin_amdgcn_mfma_f32_16x16x32_bf16(af, bf, acc[jt], 0, 0, 0);
            }
        }

        // h = (1-a)h + a*(z+xw); r = tanh(h+b); a = g*r -> LDS (C-layout)
#pragma unroll
        for (int jt = 0; jt < 8; ++jt) {
#pragma unroll
            for (int r = 0; r < 4; ++r) {
                float hv = hreg[jt][r];
                hv = (1.0f - ALPHA) * hv + ALPHA * acc[jt][r];
                hreg[jt][r] = hv;
                float av = gvr[jt] * tanh_fast(hv + bvr[jt]);
                a_lds[cur][q * 4 + r][j0 + jt * 16 + n] = f2b(av);
            }
        }
        __syncthreads();
        do_out(t, cur);
    }
}

extern "C" void kernel_launch(void* const* d_in, const int* in_sizes, int n_in,
                              void* d_out, int out_size, void* d_ws, size_t ws_size,
                              hipStream_t stream) {
    const float* x    = (const float*)d_in[0];
    const float* wi   = (const float*)d_in[1];
    const float* wrec = (const float*)d_in[2];
    const float* wout = (const float*)d_in[3];
    const float* bb   = (const float*)d_in[4];
    const float* gg   = (const float*)d_in[5];
    const float* h0   = (const float*)d_in[6];

    unsigned short* wrecB = (unsigned short*)d_ws;             // H*H   u16 = 2 MB
    unsigned short* wiT   = wrecB + (size_t)H * H;             // H*I   u16 = 256 KB
    unsigned short* woutT = wiT + (size_t)H * I_DIM;           // O*H   u16 = 256 KB
    float* outp = (float*)d_out;

    int prep_elems = H * H + H * I_DIM + O_DIM * H;
    hipLaunchKernelGGL(prep_kernel, dim3((prep_elems + 255) / 256), dim3(256), 0, stream,
                       wi, wrec, wout, wrecB, wiT, woutT);
    hipLaunchKernelGGL(rnn_kernel, dim3(4), dim3(512), 0, stream,
                       x, wrecB, bb, gg, h0, wiT, woutT, outp);
}

// Round 3
// 2181.170 us; speedup vs baseline: 15.3916x; 15.3916x over previous
//
#include <hip/hip_runtime.h>

#define H 1024
#define I_DIM 128
#define O_DIM 128
#define T_DIM 512
#define ALPHA 0.2f
#define NWG 64          // 4 batch-groups x 16 j-slices
#define JSL 64          // j rows per WG

typedef short short8 __attribute__((ext_vector_type(8)));
typedef float f32x4 __attribute__((ext_vector_type(4)));

__device__ __forceinline__ unsigned short f2b(float f) {
    union { float f; unsigned u; } x; x.f = f;
    unsigned u = x.u;
    return (unsigned short)((u + 0x7FFFu + ((u >> 16) & 1u)) >> 16);
}
__device__ __forceinline__ float tanh_fast(float x) {
    float e = __expf(2.0f * x);
    return 1.0f - 2.0f * __builtin_amdgcn_rcpf(e + 1.0f);
}
// 8 contiguous f32 -> bf16 A/B fragment (RNE)
__device__ __forceinline__ short8 ld8f(const float* __restrict__ p) {
    const float4 a = *(const float4*)p;
    const float4 b = *(const float4*)(p + 4);
    short8 r;
    r[0]=(short)f2b(a.x); r[1]=(short)f2b(a.y); r[2]=(short)f2b(a.z); r[3]=(short)f2b(a.w);
    r[4]=(short)f2b(b.x); r[5]=(short)f2b(b.y); r[6]=(short)f2b(b.z); r[7]=(short)f2b(b.w);
    return r;
}
// async global->LDS, 16B/lane; lds base must be wave-uniform
__device__ __forceinline__ void async16(const unsigned short* g, unsigned short* l) {
    __builtin_amdgcn_global_load_lds(
        (const __attribute__((address_space(1))) unsigned int*)(const void*)g,
        (__attribute__((address_space(3))) unsigned int*)(void*)l, 16, 0, 0);
}

// Packed-A layout per batch-group: element A[m][k] (m=batch 0..15, k=0..1023) at
// u16 offset: (k>>5)*512 + ((k&31)>>3)*128 + m*8 + (k&7)  -> ds_read_b128 lane-linear.
__global__ __launch_bounds__(256, 1) void rnn_kernel(
    const float* __restrict__ x, const float* __restrict__ wi,
    const float* __restrict__ wrec, const float* __restrict__ wout,
    const float* __restrict__ bb, const float* __restrict__ gg,
    const float* __restrict__ h0p, float* __restrict__ out,
    unsigned short* __restrict__ aG, unsigned int* __restrict__ bar)
{
    __shared__ unsigned short abuf[32 * 512];   // 32 KB: current a_{t-1}, packed-A
    __shared__ unsigned short aloc[2 * 512];    // 2 KB: own a_t slice, packed-A (local k)

    const int tid  = threadIdx.x;
    const int w    = tid >> 6, lane = tid & 63;
    const int n    = lane & 15, q = lane >> 4;
    const int grp  = blockIdx.x & 3;        // batch group (16 rows)
    const int ji   = blockIdx.x >> 2;       // j slice
    const int j0   = ji * JSL;
    const int j    = j0 + w * 16 + n;       // this lane's j row (B-operand col)
    const int b0   = grp * 16;

    // ---- register-resident weight fragments (loaded once, f32 -> bf16) ----
    short8 wfr[32];                          // wrec: B[k][n=j] = wrec[j][k], k-contig
#pragma unroll
    for (int kt = 0; kt < 32; ++kt)
        wfr[kt] = ld8f(&wrec[(size_t)j * H + kt * 32 + q * 8]);

    short8 wifr[4];                          // wi: B[k][n=j] = wi[k][j], stride-H
#pragma unroll
    for (int kt = 0; kt < 4; ++kt) {
        short8 v;
#pragma unroll
        for (int i = 0; i < 8; ++i)
            v[i] = (short)f2b(wi[(size_t)(kt * 32 + q * 8 + i) * H + j]);
        wifr[kt] = v;
    }
    short8 wofr[2][2];                       // wout k-slice [j0,j0+64): B[k][o]
#pragma unroll
    for (int oti = 0; oti < 2; ++oti)
#pragma unroll
        for (int ktl = 0; ktl < 2; ++ktl) {
            short8 v; const int o = (2 * w + oti) * 16 + n;
#pragma unroll
            for (int i = 0; i < 8; ++i)
                v[i] = (short)f2b(wout[(size_t)(j0 + ktl * 32 + q * 8 + i) * O_DIM + o]);
            wofr[oti][ktl] = v;
        }

    const float gv = gg[j], bv = bb[j];
    const float h00 = h0p[j];
    float hreg[4];
#pragma unroll
    for (int r = 0; r < 4; ++r) hreg[r] = h00;

    // packed offsets for this lane's produced a values (4 batch rows m=4q+r)
    const int off_g = (j >> 5) * 512 + ((j & 31) >> 3) * 128 + (j & 7);
    const int kl    = w * 16 + n;            // local k within WG's 64-slice
    const int off_l = (kl >> 5) * 512 + ((kl & 31) >> 3) * 128 + (kl & 7);

    // out_t k-partial: A = own a_t slice (aloc), B = wofr; atomicAdd f32
    auto do_out = [&](int t) {
        short8 af0 = *(const short8*)&aloc[lane * 8];
        short8 af1 = *(const short8*)&aloc[512 + lane * 8];
        f32x4 o0 = {0.f,0.f,0.f,0.f}, o1 = {0.f,0.f,0.f,0.f};
        o0 = __builtin_amdgcn_mfma_f32_16x16x32_bf16(af0, wofr[0][0], o0, 0,0,0);
        o1 = __builtin_amdgcn_mfma_f32_16x16x32_bf16(af0, wofr[1][0], o1, 0,0,0);
        o0 = __builtin_amdgcn_mfma_f32_16x16x32_bf16(af1, wofr[0][1], o0, 0,0,0);
        o1 = __builtin_amdgcn_mfma_f32_16x16x32_bf16(af1, wofr[1][1], o1, 0,0,0);
#pragma unroll
        for (int r = 0; r < 4; ++r) {
            size_t row = ((size_t)(b0 + 4*q + r) * T_DIM + t) * O_DIM;
            atomicAdd(&out[row + (2*w + 0)*16 + n], o0[r]);
            atomicAdd(&out[row + (2*w + 1)*16 + n], o1[r]);
        }
    };

    // ---- init: a0 = g*tanh(h0+b), batch-broadcast ----
    {
        unsigned short a0 = f2b(gv * tanh_fast(h00 + bv));
        unsigned short* d0 = aG + (size_t)grp * 16384;   // buf 0
#pragma unroll
        for (int r = 0; r < 4; ++r) {
            d0[off_g + (4*q + r) * 8] = a0;
            aloc[off_l + (4*q + r) * 8] = a0;
        }
    }
    __syncthreads();
    if (tid == 0) __hip_atomic_fetch_add(bar, 1u, __ATOMIC_RELEASE, __HIP_MEMORY_SCOPE_AGENT);

    short8 xfr[4];                           // prefetch x[:,0,:]
#pragma unroll
    for (int kt = 0; kt < 4; ++kt)
        xfr[kt] = ld8f(&x[(size_t)(b0 + n) * T_DIM * I_DIM + kt * 32 + q * 8]);

    do_out(0);

    for (int t = 1; t < T_DIM; ++t) {
        // wait until all WGs published a_{t-1}
        if (tid == 0) {
            const unsigned target = (unsigned)NWG * (unsigned)t;
            while (__hip_atomic_load(bar, __ATOMIC_ACQUIRE, __HIP_MEMORY_SCOPE_AGENT) < target)
                __builtin_amdgcn_s_sleep(1);
        }
        __syncthreads();

        // copy a_{t-1} (32 KB packed) -> LDS
        const unsigned short* src = aG + ((size_t)((t - 1) & 1) * 4 + grp) * 16384;
#pragma unroll
        for (int c = 0; c < 8; ++c) {
            const int chunk = w * 8 + c;
            async16(src + chunk * 512 + lane * 8, abuf + chunk * 512);
        }
        __syncthreads();

        // z = x_{t-1}@wi + a_{t-1}@wrec^T  (two interleaved acc chains)
        f32x4 acc0 = {0.f,0.f,0.f,0.f}, acc1 = {0.f,0.f,0.f,0.f};
        acc0 = __builtin_amdgcn_mfma_f32_16x16x32_bf16(xfr[0], wifr[0], acc0, 0,0,0);
        acc1 = __builtin_amdgcn_mfma_f32_16x16x32_bf16(xfr[1], wifr[1], acc1, 0,0,0);
        acc0 = __builtin_amdgcn_mfma_f32_16x16x32_bf16(xfr[2], wifr[2], acc0, 0,0,0);
        acc1 = __builtin_amdgcn_mfma_f32_16x16x32_bf16(xfr[3], wifr[3], acc1, 0,0,0);
#pragma unroll
        for (int kt = 0; kt < 32; kt += 2) {
            short8 a0f = *(const short8*)&abuf[kt * 512 + lane * 8];
            short8 a1f = *(const short8*)&abuf[(kt + 1) * 512 + lane * 8];
            acc0 = __builtin_amdgcn_mfma_f32_16x16x32_bf16(a0f, wfr[kt],     acc0, 0,0,0);
            acc1 = __builtin_amdgcn_mfma_f32_16x16x32_bf16(a1f, wfr[kt + 1], acc1, 0,0,0);
        }

        // h update + publish a_t
        unsigned short* dst = aG + ((size_t)(t & 1) * 4 + grp) * 16384;
#pragma unroll
        for (int r = 0; r < 4; ++r) {
            float z  = acc0[r] + acc1[r];
            float hv = (1.0f - ALPHA) * hreg[r] + ALPHA * z;
            hreg[r] = hv;
            unsigned short ab = f2b(gv * tanh_fast(hv + bv));
            dst[off_g + (4*q + r) * 8] = ab;
            aloc[off_l + (4*q + r) * 8] = ab;
        }
        __syncthreads();   // drain all lanes' stores (wave-level vmcnt) + aloc visible
        if (tid == 0) __hip_atomic_fetch_add(bar, 1u, __ATOMIC_RELEASE, __HIP_MEMORY_SCOPE_AGENT);

        // overlap with other WGs' progress: x prefetch + out partial
        if (t < T_DIM - 1) {
#pragma unroll
            for (int kt = 0; kt < 4; ++kt)
                xfr[kt] = ld8f(&x[((size_t)(b0 + n) * T_DIM + t) * I_DIM + kt * 32 + q * 8]);
        }
        do_out(t);
    }
}

extern "C" void kernel_launch(void* const* d_in, const int* in_sizes, int n_in,
                              void* d_out, int out_size, void* d_ws, size_t ws_size,
                              hipStream_t stream) {
    const float* x    = (const float*)d_in[0];
    const float* wi   = (const float*)d_in[1];
    const float* wrec = (const float*)d_in[2];
    const float* wout = (const float*)d_in[3];
    const float* bb   = (const float*)d_in[4];
    const float* gg   = (const float*)d_in[5];
    const float* h0   = (const float*)d_in[6];
    float* outp = (float*)d_out;

    unsigned short* aG = (unsigned short*)d_ws;                       // 2 x 4 x 16384 u16 = 256 KB
    unsigned int* bar  = (unsigned int*)((char*)d_ws + 2 * 4 * 16384 * 2);

    hipMemsetAsync(d_out, 0, (size_t)64 * T_DIM * O_DIM * sizeof(float), stream);
    hipMemsetAsync(bar, 0, 64, stream);
    hipLaunchKernelGGL(rnn_kernel, dim3(NWG), dim3(256), 0, stream,
                       x, wi, wrec, wout, bb, gg, h0, outp, aG, bar);
}

// Round 4
// 2120.836 us; speedup vs baseline: 15.8295x; 1.0284x over previous
//
#include <hip/hip_runtime.h>

#define H 1024
#define I_DIM 128
#define O_DIM 128
#define T_DIM 512
#define ALPHA 0.2f
#define NWG 64          // 4 batch-groups x 16 j-slices
#define GSZ 16          // WGs per batch-group

typedef short short8 __attribute__((ext_vector_type(8)));
typedef float f32x4 __attribute__((ext_vector_type(4)));

__device__ __forceinline__ unsigned short f2b(float f) {
    union { float f; unsigned u; } x; x.f = f;
    unsigned u = x.u;
    return (unsigned short)((u + 0x7FFFu + ((u >> 16) & 1u)) >> 16);
}
__device__ __forceinline__ float tanh_fast(float x) {
    float e = __expf(2.0f * x);
    return 1.0f - 2.0f * __builtin_amdgcn_rcpf(e + 1.0f);
}
// 8 contiguous f32 -> bf16 fragment (RNE)
__device__ __forceinline__ short8 ld8f(const float* __restrict__ p) {
    const float4 a = *(const float4*)p;
    const float4 b = *(const float4*)(p + 4);
    short8 r;
    r[0]=(short)f2b(a.x); r[1]=(short)f2b(a.y); r[2]=(short)f2b(a.z); r[3]=(short)f2b(a.w);
    r[4]=(short)f2b(b.x); r[5]=(short)f2b(b.y); r[6]=(short)f2b(b.z); r[7]=(short)f2b(b.w);
    return r;
}
__device__ __forceinline__ void async16(const unsigned short* g, unsigned short* l) {
    __builtin_amdgcn_global_load_lds(
        (const __attribute__((address_space(1))) unsigned int*)(const void*)g,
        (__attribute__((address_space(3))) unsigned int*)(void*)l, 16, 0, 0);
}

// Packed-A layout per batch-group: A[m][k] at u16 offset
//   (k>>5)*512 + ((k&31)>>3)*128 + m*8 + (k&7)
// -> A-fragment read is ds_read_b128 at abuf[kblock*512 + lane*8] (conflict-free).
// WG (grp, ji)'s produced slice (k in [ji*64, ji*64+64)) is CONTIGUOUS: 2 KB at
// u16 offset ji*1024 within the group's 32 KB buffer.
__global__ __launch_bounds__(256, 1) void rnn_kernel(
    const float* __restrict__ x, const float* __restrict__ wi,
    const float* __restrict__ wrec, const float* __restrict__ wout,
    const float* __restrict__ bb, const float* __restrict__ gg,
    const float* __restrict__ h0p, float* __restrict__ out,
    unsigned short* __restrict__ aG, unsigned int* __restrict__ bar)
{
    __shared__ unsigned short abuf[32 * 512];   // 32 KB: group's full a_{t-1}
    __shared__ unsigned short aloc[1024];       // 2 KB: own a_t slice, packed, contiguous
    __shared__ float opart[4 * 128];            // 2 KB: out k-partials (4 waves)

    const int tid  = threadIdx.x;
    const int w    = tid >> 6, lane = tid & 63;
    const int n    = lane & 15, q = lane >> 4;
    const int grp  = blockIdx.x & 3;
    const int ji   = blockIdx.x >> 2;
    const int j0   = ji * 64;
    const int j    = j0 + w * 16 + n;           // this lane's owned h row
    const int b0   = grp * 16;
    unsigned int* gbar = bar + grp * 64;        // per-group barrier, 256B apart

    // ---- register-resident weights (f32 -> bf16, once) ----
    short8 wfr[32];                              // wrec B-frags: B[k][j] = wrec[j][k]
#pragma unroll
    for (int kt = 0; kt < 32; ++kt)
        wfr[kt] = ld8f(&wrec[(size_t)j * H + kt * 32 + q * 8]);

    short8 wifr[4];                              // wi B-frags: B[k][j] = wi[k][j]
#pragma unroll
    for (int kt = 0; kt < 4; ++kt) {
        short8 v;
#pragma unroll
        for (int i = 0; i < 8; ++i)
            v[i] = (short)f2b(wi[(size_t)(kt * 32 + q * 8 + i) * H + j]);
        wifr[kt] = v;
    }
    short8 wofr[8];                              // wout B-frags, cols ji*8..+8, zero-pad n>=8
#pragma unroll
    for (int kk = 0; kk < 8; ++kk) {
        short8 v;
        const int kb = (w * 8 + kk) * 32 + q * 8;
#pragma unroll
        for (int i = 0; i < 8; ++i)
            v[i] = (n < 8) ? (short)f2b(wout[(size_t)(kb + i) * O_DIM + ji * 8 + n]) : (short)0;
        wofr[kk] = v;
    }

    const float gv = gg[j], bv = bb[j], h00 = h0p[j];
    float hreg[4];
#pragma unroll
    for (int r = 0; r < 4; ++r) hreg[r] = h00;

    const int kl    = w * 16 + n;                // local k in [0,64)
    const int off_l = (kl >> 5) * 512 + ((kl & 31) >> 3) * 128 + (kl & 7);

    // out[:, t, ji*8..+8) computed fully from abuf (= a_t) with k=1024 chain.
    auto do_out = [&](int t) {
        f32x4 oa = {0.f, 0.f, 0.f, 0.f};
#pragma unroll
        for (int kk = 0; kk < 8; ++kk) {
            short8 af = *(const short8*)&abuf[(w * 8 + kk) * 512 + lane * 8];
            oa = __builtin_amdgcn_mfma_f32_16x16x32_bf16(af, wofr[kk], oa, 0, 0, 0);
        }
        if (n < 8) {
#pragma unroll
            for (int r = 0; r < 4; ++r) opart[w * 128 + (4 * q + r) * 8 + n] = oa[r];
        }
        __syncthreads();
        if (tid < 128) {
            float s = opart[tid] + opart[128 + tid] + opart[256 + tid] + opart[384 + tid];
            const int m = tid >> 3, c = tid & 7;
            out[((size_t)(b0 + m) * T_DIM + t) * O_DIM + ji * 8 + c] = s;
        }
    };

    // ---- init: publish a0 = g*tanh(h0+b) (batch-broadcast) ----
    {
        unsigned short a0 = f2b(gv * tanh_fast(h00 + bv));
        unsigned short* d0 = aG + (size_t)grp * 16384 + ji * 1024;  // buf 0
#pragma unroll
        for (int r = 0; r < 4; ++r) d0[off_l + (4 * q + r) * 8] = a0;
    }
    __syncthreads();
    if (tid == 0) __hip_atomic_fetch_add(gbar, 1u, __ATOMIC_RELEASE, __HIP_MEMORY_SCOPE_AGENT);

    short8 xfr[4];                               // prefetch x[:,0,:]
#pragma unroll
    for (int kt = 0; kt < 4; ++kt)
        xfr[kt] = ld8f(&x[(size_t)(b0 + n) * T_DIM * I_DIM + kt * 32 + q * 8]);

    for (int t = 1; t < T_DIM; ++t) {
        // x@wi partials first: register-only, overlaps other WGs finishing
        f32x4 acc0 = {0.f,0.f,0.f,0.f}, acc1 = {0.f,0.f,0.f,0.f};
        acc0 = __builtin_amdgcn_mfma_f32_16x16x32_bf16(xfr[0], wifr[0], acc0, 0,0,0);
        acc1 = __builtin_amdgcn_mfma_f32_16x16x32_bf16(xfr[1], wifr[1], acc1, 0,0,0);
        acc0 = __builtin_amdgcn_mfma_f32_16x16x32_bf16(xfr[2], wifr[2], acc0, 0,0,0);
        acc1 = __builtin_amdgcn_mfma_f32_16x16x32_bf16(xfr[3], wifr[3], acc1, 0,0,0);

        // wait for group to publish a_{t-1}
        if (tid == 0) {
            const unsigned target = (unsigned)GSZ * (unsigned)t;
            while (__hip_atomic_load(gbar, __ATOMIC_ACQUIRE, __HIP_MEMORY_SCOPE_AGENT) < target)
                __builtin_amdgcn_s_sleep(1);
        }
        __syncthreads();

        // a_{t-1} (32 KB packed) -> LDS
        const unsigned short* src = aG + ((size_t)((t - 1) & 1) * 4 + grp) * 16384;
#pragma unroll
        for (int c = 0; c < 8; ++c) {
            const int chunk = w * 8 + c;
            async16(src + chunk * 512 + lane * 8, abuf + chunk * 512);
        }
        __syncthreads();

        // + a_{t-1} @ wrec^T
#pragma unroll
        for (int kt = 0; kt < 32; kt += 2) {
            short8 a0f = *(const short8*)&abuf[kt * 512 + lane * 8];
            short8 a1f = *(const short8*)&abuf[(kt + 1) * 512 + lane * 8];
            acc0 = __builtin_amdgcn_mfma_f32_16x16x32_bf16(a0f, wfr[kt],     acc0, 0,0,0);
            acc1 = __builtin_amdgcn_mfma_f32_16x16x32_bf16(a1f, wfr[kt + 1], acc1, 0,0,0);
        }

        // h update; stage a_t in aloc (packed, contiguous 2 KB)
#pragma unroll
        for (int r = 0; r < 4; ++r) {
            float z  = acc0[r] + acc1[r];
            float hv = (1.0f - ALPHA) * hreg[r] + ALPHA * z;
            hreg[r] = hv;
            aloc[off_l + (4 * q + r) * 8] = f2b(gv * tanh_fast(hv + bv));
        }
        __syncthreads();

        // wide publish: 128 x 16B contiguous stores
        unsigned short* dst = aG + ((size_t)(t & 1) * 4 + grp) * 16384 + ji * 1024;
        if (tid < 128) *(short8*)(dst + tid * 8) = *(const short8*)&aloc[tid * 8];
        __syncthreads();
        if (tid == 0) __hip_atomic_fetch_add(gbar, 1u, __ATOMIC_RELEASE, __HIP_MEMORY_SCOPE_AGENT);

        // out for step t-1 from abuf (complete k-chain, no atomics)
        do_out(t - 1);

        // prefetch x[:,t,:] for next iteration
        if (t < T_DIM - 1) {
#pragma unroll
            for (int kt = 0; kt < 4; ++kt)
                xfr[kt] = ld8f(&x[((size_t)(b0 + n) * T_DIM + t) * I_DIM + kt * 32 + q * 8]);
        }
    }

    // epilogue: out[:, 511, :] from a_511
    if (tid == 0) {
        const unsigned target = (unsigned)GSZ * (unsigned)T_DIM;
        while (__hip_atomic_load(gbar, __ATOMIC_ACQUIRE, __HIP_MEMORY_SCOPE_AGENT) < target)
            __builtin_amdgcn_s_sleep(1);
    }
    __syncthreads();
    const unsigned short* src = aG + ((size_t)((T_DIM - 1) & 1) * 4 + grp) * 16384;
#pragma unroll
    for (int c = 0; c < 8; ++c) {
        const int chunk = w * 8 + c;
        async16(src + chunk * 512 + lane * 8, abuf + chunk * 512);
    }
    __syncthreads();
    do_out(T_DIM - 1);
}

extern "C" void kernel_launch(void* const* d_in, const int* in_sizes, int n_in,
                              void* d_out, int out_size, void* d_ws, size_t ws_size,
                              hipStream_t stream) {
    const float* x    = (const float*)d_in[0];
    const float* wi   = (const float*)d_in[1];
    const float* wrec = (const float*)d_in[2];
    const float* wout = (const float*)d_in[3];
    const float* bb   = (const float*)d_in[4];
    const float* gg   = (const float*)d_in[5];
    const float* h0   = (const float*)d_in[6];
    float* outp = (float*)d_out;

    unsigned short* aG = (unsigned short*)d_ws;                  // 2 x 4 x 16384 u16 = 256 KB
    unsigned int* bar  = (unsigned int*)((char*)d_ws + 2 * 4 * 16384 * 2);

    hipMemsetAsync(bar, 0, 1024, stream);
    hipLaunchKernelGGL(rnn_kernel, dim3(NWG), dim3(256), 0, stream,
                       x, wi, wrec, wout, bb, gg, h0, outp, aG, bar);
}